// Round 3
// baseline (388.341 us; speedup 1.0000x reference)
//
#include <hip/hip_runtime.h>
#include <hip/hip_bf16.h>

// B=8, S=512 -> TOK=4096 tokens, D=1024, F=2048, H=16 heads, O=1.
#define TOK 4096
#define DD  1024
#define FF  2048
#define NH  16

typedef short bf16x8 __attribute__((ext_vector_type(8)));
typedef float f32x4  __attribute__((ext_vector_type(4)));

__device__ __forceinline__ float gelu_f(float x) {
  float u = 0.7978845608028654f * (x + 0.044715f * x * x * x);
  float e = __expf(2.0f * u);
  return 0.5f * x * (2.0f - 2.0f / (e + 1.0f));
}

// fp32 -> bf16 round-to-nearest-even
__device__ __forceinline__ unsigned short f2bf(float f) {
  union { float f; unsigned u; } v; v.f = f;
  unsigned r = v.u + 0x7FFF + ((v.u >> 16) & 1);
  return (unsigned short)(r >> 16);
}
__device__ __forceinline__ unsigned pack2(float a, float b) {
  return (unsigned)f2bf(a) | ((unsigned)f2bf(b) << 16);
}

// async global->LDS, 16 bytes per lane; LDS dst = wave-uniform base + lane*16
__device__ __forceinline__ void load_lds16(const void* g, void* l) {
  __builtin_amdgcn_global_load_lds(
      (const __attribute__((address_space(1))) void*)g,
      (__attribute__((address_space(3))) void*)l, 16, 0, 0);
}

// ---------------------------------------------------------------------------
// prep_xr: fused routing + X build.
//   X[t][k] = (emb_s[sid]+emb_t[tsk]+v*val_vec)*mask -> bf16 row-major Xb.
//   One thread per 8-element chunk; the kc==0 thread of each token also does
//   routing (head list append + out init with b2[h] / 0).
// ---------------------------------------------------------------------------
__global__ __launch_bounds__(256) void prep_xr(
    const int* __restrict__ selfies, const int* __restrict__ tasks,
    const float* __restrict__ values, const int* __restrict__ pmask,
    const float* __restrict__ emb_s, const float* __restrict__ emb_t,
    const float* __restrict__ val_vec, const float* __restrict__ b2,
    unsigned short* __restrict__ Xb, int* __restrict__ counts,
    int* __restrict__ lists, float* __restrict__ out) {
  int gid = blockIdx.x * 256 + threadIdx.x;   // TOK*128 threads
  int kc = (gid & 127) * 8;
  int t  = gid >> 7;
  int sid = selfies[t], tsk = tasks[t];
  if ((gid & 127) == 0) {
    if (tsk > 0) {
      int h = (tsk - 1) & (NH - 1);
      int pos = atomicAdd(&counts[h], 1);
      lists[h * TOK + pos] = t;
      out[t] = b2[h];
    } else {
      out[t] = 0.0f;
    }
  }
  float v = values[t];
  float msk = pmask[t] ? 1.0f : 0.0f;
  const float* ps = emb_s + (size_t)sid * DD + kc;
  const float* pt = emb_t + (size_t)tsk * DD + kc;
  const float* pv = val_vec + kc;
  float r[8];
#pragma unroll
  for (int j = 0; j < 8; j += 4) {
    float4 a = *(const float4*)(ps + j);
    float4 b = *(const float4*)(pt + j);
    float4 c = *(const float4*)(pv + j);
    r[j + 0] = (a.x + b.x + v * c.x) * msk;
    r[j + 1] = (a.y + b.y + v * c.y) * msk;
    r[j + 2] = (a.z + b.z + v * c.z) * msk;
    r[j + 3] = (a.w + b.w + v * c.w) * msk;
  }
  uint4 o;
  o.x = pack2(r[0], r[1]); o.y = pack2(r[2], r[3]);
  o.z = pack2(r[4], r[5]); o.w = pack2(r[6], r[7]);
  *(uint4*)(Xb + (size_t)gid * 8) = o;
}

// ---------------------------------------------------------------------------
// prep_w: transpose+pack Ws and W1 (fp32 k-major) into bf16 MFMA-frag-major.
// Chunk layout: cid = ((mat_sel*... NT)*32 + kc2)*64 + lane, 8 bf16/chunk:
//   value j = W[kc2*32 + (lane>>4)*8 + j][NT*16 + (lane&15)]
// Each thread produces an NT-PAIR (NT0=2*ntp, NT0+1) so the two 64B halves of
// each 128B line are requested back-to-back (full line utilization via L2).
// ---------------------------------------------------------------------------
__global__ __launch_bounds__(256) void prep_w(
    const float* __restrict__ Ws, const float* __restrict__ W1,
    unsigned short* __restrict__ Wsp, unsigned short* __restrict__ W1p) {
  const int W1_PAIRS = 16 * 64 * 32 * 64;   // h(16) x ntp(64) x kc2(32) x lane(64)
  int cid2 = blockIdx.x * 256 + threadIdx.x;
  const float* src0;
  unsigned short *dst0, *dst1;
  int stride;
  if (cid2 < W1_PAIRS) {
    int lane = cid2 & 63, kc2 = (cid2 >> 6) & 31, ntp = (cid2 >> 11) & 63, h = cid2 >> 17;
    int q = lane >> 4, c = lane & 15;
    src0 = W1 + ((size_t)h * DD + kc2 * 32 + q * 8) * FF + ntp * 32 + c;
    size_t c0 = (((size_t)h * 128 + ntp * 2) * 32 + kc2) * 64 + lane;
    dst0 = W1p + c0 * 8;
    dst1 = W1p + (c0 + 32 * 64) * 8;    // NT+1 -> +32*64 chunks
    stride = FF;
  } else {
    int cid3 = cid2 - W1_PAIRS;          // < 32*32*64 (ntp(32) x kc2(32) x lane(64))
    int lane = cid3 & 63, kc2 = (cid3 >> 6) & 31, ntp = cid3 >> 11;
    int q = lane >> 4, c = lane & 15;
    src0 = Ws + ((size_t)kc2 * 32 + q * 8) * DD + ntp * 32 + c;
    size_t c0 = ((size_t)(ntp * 2) * 32 + kc2) * 64 + lane;
    dst0 = Wsp + c0 * 8;
    dst1 = Wsp + (c0 + 32 * 64) * 8;
    stride = DD;
  }
  float r0[8], r1[8];
#pragma unroll
  for (int j = 0; j < 8; ++j) {
    r0[j] = src0[(size_t)j * stride];
    r1[j] = src0[(size_t)j * stride + 16];
  }
  uint4 o0, o1;
  o0.x = pack2(r0[0], r0[1]); o0.y = pack2(r0[2], r0[3]);
  o0.z = pack2(r0[4], r0[5]); o0.w = pack2(r0[6], r0[7]);
  o1.x = pack2(r1[0], r1[1]); o1.y = pack2(r1[2], r1[3]);
  o1.z = pack2(r1[4], r1[5]); o1.w = pack2(r1[6], r1[7]);
  *(uint4*)dst0 = o0;
  *(uint4*)dst1 = o1;
}

// ---------------------------------------------------------------------------
// Stage 1: shared = gelu(X @ Ws + bs). Block = 64m x 128n, BK=64, 4 waves,
// wave = 64m x 32n. A: LDS double-buffer via global_load_lds (only 2 loads
// drained per barrier). B: frag-major register loads from Wsp, prefetched
// one K-step ahead (never crosses the barrier as an outstanding LDS op).
// ---------------------------------------------------------------------------
__global__ __launch_bounds__(256, 2) void gemm1_mfma(
    const unsigned short* __restrict__ Xb, const unsigned short* __restrict__ Wsp,
    const float* __restrict__ bs, unsigned short* __restrict__ shared_bf) {
  __shared__ __align__(16) unsigned short As[2][4096];   // 2 x 8 KB

  const int tid = threadIdx.x;
  const int lane = tid & 63, w = tid >> 6;
  const int m0 = blockIdx.x * 64;
  const int n0 = blockIdx.y * 128;
  const int q = lane >> 4, c = lane & 15;

  // A staging: wave w stages rows m0 + w*16 + c (its own mt=w tile), both kk.
  const unsigned short* aSrc = Xb + (size_t)(m0 + w * 16 + c) * DD + q * 8;

  // B frag pointers: NT = blockIdx.y*8 + w*2 + t; chunk = (NT*32 + kc2)*64 + lane
  const unsigned short* bPtr[2];
#pragma unroll
  for (int t = 0; t < 2; ++t)
    bPtr[t] = Wsp + (((size_t)(blockIdx.y * 8 + w * 2 + t) * 32) * 64 + lane) * 8;

  f32x4 acc[4][2] = {};
  bf16x8 bc[2][2], bn[2][2];

  // Preload step 0.
  load_lds16(aSrc, &As[0][(size_t)(0 * 256 + w * 64 + lane) * 8]);
  load_lds16(aSrc + 32, &As[0][(size_t)(1 * 256 + w * 64 + lane) * 8]);
#pragma unroll
  for (int kk = 0; kk < 2; ++kk)
#pragma unroll
    for (int t = 0; t < 2; ++t)
      bc[kk][t] = *(const bf16x8*)(bPtr[t] + (size_t)kk * 512);
  __syncthreads();

#pragma unroll
  for (int s = 0; s < 16; ++s) {
    const int p = s & 1;
    bf16x8 a[2][4];
#pragma unroll
    for (int kk = 0; kk < 2; ++kk)
#pragma unroll
      for (int mt = 0; mt < 4; ++mt)
        a[kk][mt] = *(const bf16x8*)&As[p][(size_t)((kk * 4 + mt) * 64 + lane) * 8];
    if (s < 15) {
      const int k1 = (s + 1) * 64;
      load_lds16(aSrc + k1, &As[1 - p][(size_t)(0 * 256 + w * 64 + lane) * 8]);
      load_lds16(aSrc + k1 + 32, &As[1 - p][(size_t)(1 * 256 + w * 64 + lane) * 8]);
#pragma unroll
      for (int kk = 0; kk < 2; ++kk)
#pragma unroll
        for (int t = 0; t < 2; ++t)
          bn[kk][t] = *(const bf16x8*)(bPtr[t] + (size_t)((s + 1) * 2 + kk) * 512);
    }
#pragma unroll
    for (int kk = 0; kk < 2; ++kk)
#pragma unroll
      for (int mt = 0; mt < 4; ++mt)
#pragma unroll
        for (int t = 0; t < 2; ++t)
          acc[mt][t] = __builtin_amdgcn_mfma_f32_16x16x32_bf16(a[kk][mt], bc[kk][t], acc[mt][t], 0, 0, 0);
    __syncthreads();
    if (s < 15) {
#pragma unroll
      for (int kk = 0; kk < 2; ++kk)
#pragma unroll
        for (int t = 0; t < 2; ++t)
          bc[kk][t] = bn[kk][t];
    }
  }

  // Epilogue: +bs, gelu, bf16 store. C layout: row = mt*16 + q*4 + r, col = nt*16 + c.
  float bsv[2];
#pragma unroll
  for (int t = 0; t < 2; ++t) bsv[t] = bs[n0 + w * 32 + t * 16 + c];
#pragma unroll
  for (int mt = 0; mt < 4; ++mt)
#pragma unroll
    for (int t = 0; t < 2; ++t)
#pragma unroll
      for (int r = 0; r < 4; ++r) {
        int row = m0 + mt * 16 + q * 4 + r;
        int col = n0 + w * 32 + t * 16 + c;
        shared_bf[(size_t)row * DD + col] = f2bf(gelu_f(acc[mt][t][r] + bsv[t]));
      }
}

// ---------------------------------------------------------------------------
// Stage 2: per-head MLP. Block = 64 tokens x 256 F, BK=64, 4 waves,
// wave = 64m x 64n. Same pipeline as gemm1 (LDS-dbuf gathered A, reg-B from
// W1p with 1-step prefetch). Epilogue: gelu(+b1) dot W2, reduce, atomicAdd.
// ---------------------------------------------------------------------------
__global__ __launch_bounds__(256, 2) void gemm2_mfma(
    const unsigned short* __restrict__ shared_bf, const unsigned short* __restrict__ W1p,
    const float* __restrict__ b1, const float* __restrict__ W2,
    const int* __restrict__ counts, const int* __restrict__ lists,
    float* __restrict__ out) {
  const int h = blockIdx.z;
  const int nt_h = counts[h];
  const int m0 = blockIdx.x * 64;
  if (m0 >= nt_h) return;
  const int fc = blockIdx.y;             // f0 = fc*256

  __shared__ __align__(16) unsigned short As[2][4096];   // 2 x 8 KB
  __shared__ int   stok[64];
  __shared__ float red[4][68];

  const int tid = threadIdx.x;
  const int lane = tid & 63, w = tid >> 6;
  const int q = lane >> 4, c = lane & 15;

  if (tid < 64) {
    int i = m0 + tid;
    stok[tid] = (i < nt_h) ? lists[h * TOK + i] : -1;
  }
  __syncthreads();

  // A staging (gathered rows; dead rows clamp to token 0, discarded in epilogue)
  int tokr = stok[w * 16 + c];
  if (tokr < 0) tokr = 0;
  const unsigned short* aSrc = shared_bf + (size_t)tokr * DD + q * 8;

  // B frag pointers: NT = fc*16 + w*4 + t
  const unsigned short* bPtr[4];
#pragma unroll
  for (int t = 0; t < 4; ++t)
    bPtr[t] = W1p + (((size_t)(h * 128 + fc * 16 + w * 4 + t) * 32) * 64 + lane) * 8;

  f32x4 acc[4][4] = {};
  bf16x8 bc[2][4], bn[2][4];

  load_lds16(aSrc, &As[0][(size_t)(0 * 256 + w * 64 + lane) * 8]);
  load_lds16(aSrc + 32, &As[0][(size_t)(1 * 256 + w * 64 + lane) * 8]);
#pragma unroll
  for (int kk = 0; kk < 2; ++kk)
#pragma unroll
    for (int t = 0; t < 4; ++t)
      bc[kk][t] = *(const bf16x8*)(bPtr[t] + (size_t)kk * 512);
  __syncthreads();

#pragma unroll
  for (int s = 0; s < 16; ++s) {
    const int p = s & 1;
    bf16x8 a[2][4];
#pragma unroll
    for (int kk = 0; kk < 2; ++kk)
#pragma unroll
      for (int mt = 0; mt < 4; ++mt)
        a[kk][mt] = *(const bf16x8*)&As[p][(size_t)((kk * 4 + mt) * 64 + lane) * 8];
    if (s < 15) {
      const int k1 = (s + 1) * 64;
      load_lds16(aSrc + k1, &As[1 - p][(size_t)(0 * 256 + w * 64 + lane) * 8]);
      load_lds16(aSrc + k1 + 32, &As[1 - p][(size_t)(1 * 256 + w * 64 + lane) * 8]);
#pragma unroll
      for (int kk = 0; kk < 2; ++kk)
#pragma unroll
        for (int t = 0; t < 4; ++t)
          bn[kk][t] = *(const bf16x8*)(bPtr[t] + (size_t)((s + 1) * 2 + kk) * 512);
    }
#pragma unroll
    for (int kk = 0; kk < 2; ++kk)
#pragma unroll
      for (int mt = 0; mt < 4; ++mt)
#pragma unroll
        for (int t = 0; t < 4; ++t)
          acc[mt][t] = __builtin_amdgcn_mfma_f32_16x16x32_bf16(a[kk][mt], bc[kk][t], acc[mt][t], 0, 0, 0);
    __syncthreads();
    if (s < 15) {
#pragma unroll
      for (int kk = 0; kk < 2; ++kk)
#pragma unroll
        for (int t = 0; t < 4; ++t)
          bc[kk][t] = bn[kk][t];
    }
  }

  // Epilogue: per lane cols n = fc*256 + w*64 + t*16 + c
  const float* b1h = b1 + (size_t)h * FF + fc * 256 + w * 64;
  const float* w2h = W2 + (size_t)h * FF + fc * 256 + w * 64;
  float b1v[4], w2v[4];
#pragma unroll
  for (int t = 0; t < 4; ++t) { b1v[t] = b1h[t * 16 + c]; w2v[t] = w2h[t * 16 + c]; }

#pragma unroll
  for (int mt = 0; mt < 4; ++mt)
#pragma unroll
    for (int r = 0; r < 4; ++r) {
      float s = 0.0f;
#pragma unroll
      for (int t = 0; t < 4; ++t)
        s += gelu_f(acc[mt][t][r] + b1v[t]) * w2v[t];
      s += __shfl_xor(s, 1);
      s += __shfl_xor(s, 2);
      s += __shfl_xor(s, 4);
      s += __shfl_xor(s, 8);
      if (c == 0) red[w][mt * 16 + q * 4 + r] = s;
    }
  __syncthreads();

  if (tid < 64) {
    int t = stok[tid];
    if (t >= 0) {
      float s = red[0][tid] + red[1][tid] + red[2][tid] + red[3][tid];
      atomicAdd(&out[t], s);
    }
  }
}

// ---------------------------------------------------------------------------
extern "C" void kernel_launch(void* const* d_in, const int* in_sizes, int n_in,
                              void* d_out, int out_size, void* d_ws, size_t ws_size,
                              hipStream_t stream) {
  const int*   selfies = (const int*)d_in[0];
  const int*   tasks   = (const int*)d_in[1];
  const float* values  = (const float*)d_in[2];
  const int*   pmask   = (const int*)d_in[3];
  const float* emb_s   = (const float*)d_in[4];
  const float* emb_t   = (const float*)d_in[5];
  const float* val_vec = (const float*)d_in[6];
  const float* Ws      = (const float*)d_in[7];
  const float* bs      = (const float*)d_in[8];
  const float* W1      = (const float*)d_in[9];
  const float* b1      = (const float*)d_in[10];
  const float* W2      = (const float*)d_in[11];
  const float* b2      = (const float*)d_in[12];
  float* out = (float*)d_out;

  // Workspace layout (256-B aligned):
  //   Xb        bf16 [4096][1024]   8 MB   @ 0
  //   shared_bf bf16 [4096][1024]   8 MB   @ 8 MB
  //   Wsp       bf16 frag-major     2 MB   @ 16 MB
  //   W1p       bf16 frag-major    64 MB   @ 18 MB
  //   counts    int[16]                    @ 82 MB
  //   lists     int[16*4096]               @ 82 MB + 256
  char* ws = (char*)d_ws;
  unsigned short* Xb        = (unsigned short*)ws;
  unsigned short* shared_bf = (unsigned short*)(ws + (8u << 20));
  unsigned short* Wsp       = (unsigned short*)(ws + (16u << 20));
  unsigned short* W1p       = (unsigned short*)(ws + (18u << 20));
  int* counts = (int*)(ws + (82u << 20));
  int* lists  = (int*)(ws + (82u << 20) + 256);

  hipMemsetAsync(counts, 0, NH * sizeof(int), stream);
  prep_xr<<<TOK * 128 / 256, 256, 0, stream>>>(selfies, tasks, values, pmask,
                                               emb_s, emb_t, val_vec, b2,
                                               Xb, counts, lists, out);
  prep_w<<<(16 * 64 * 32 * 64 + 32 * 32 * 64) / 256, 256, 0, stream>>>(Ws, W1, Wsp, W1p);
  gemm1_mfma<<<dim3(TOK / 64, DD / 128), 256, 0, stream>>>(Xb, Wsp, bs, shared_bf);
  gemm2_mfma<<<dim3(8, FF / 256, NH), 256, 0, stream>>>(shared_bf, W1p, b1, W2,
                                                        counts, lists, out);
}

// Round 4
// 372.124 us; speedup vs baseline: 1.0436x; 1.0436x over previous
//
#include <hip/hip_runtime.h>
#include <hip/hip_bf16.h>

// B=8, S=512 -> TOK=4096 tokens, D=1024, F=2048, H=16 heads, O=1.
#define TOK 4096
#define DD  1024
#define FF  2048
#define NH  16

typedef short bf16x8 __attribute__((ext_vector_type(8)));
typedef float f32x4  __attribute__((ext_vector_type(4)));

__device__ __forceinline__ float gelu_f(float x) {
  float u = 0.7978845608028654f * (x + 0.044715f * x * x * x);
  float e = __expf(2.0f * u);
  return 0.5f * x * (2.0f - 2.0f / (e + 1.0f));
}

// fp32 -> bf16 round-to-nearest-even
__device__ __forceinline__ unsigned short f2bf(float f) {
  union { float f; unsigned u; } v; v.f = f;
  unsigned r = v.u + 0x7FFF + ((v.u >> 16) & 1);
  return (unsigned short)(r >> 16);
}
__device__ __forceinline__ unsigned pack2(float a, float b) {
  return (unsigned)f2bf(a) | ((unsigned)f2bf(b) << 16);
}

// ---------------------------------------------------------------------------
// prep_xr: fused routing + X build (bf16 row-major Xb).
// ---------------------------------------------------------------------------
__global__ __launch_bounds__(256) void prep_xr(
    const int* __restrict__ selfies, const int* __restrict__ tasks,
    const float* __restrict__ values, const int* __restrict__ pmask,
    const float* __restrict__ emb_s, const float* __restrict__ emb_t,
    const float* __restrict__ val_vec, const float* __restrict__ b2,
    unsigned short* __restrict__ Xb, int* __restrict__ counts,
    int* __restrict__ lists, float* __restrict__ out) {
  int gid = blockIdx.x * 256 + threadIdx.x;   // TOK*128 threads
  int kc = (gid & 127) * 8;
  int t  = gid >> 7;
  int sid = selfies[t], tsk = tasks[t];
  if ((gid & 127) == 0) {
    if (tsk > 0) {
      int h = (tsk - 1) & (NH - 1);
      int pos = atomicAdd(&counts[h], 1);
      lists[h * TOK + pos] = t;
      out[t] = b2[h];
    } else {
      out[t] = 0.0f;
    }
  }
  float v = values[t];
  float msk = pmask[t] ? 1.0f : 0.0f;
  const float* ps = emb_s + (size_t)sid * DD + kc;
  const float* pt = emb_t + (size_t)tsk * DD + kc;
  const float* pv = val_vec + kc;
  float r[8];
#pragma unroll
  for (int j = 0; j < 8; j += 4) {
    float4 a = *(const float4*)(ps + j);
    float4 b = *(const float4*)(pt + j);
    float4 c = *(const float4*)(pv + j);
    r[j + 0] = (a.x + b.x + v * c.x) * msk;
    r[j + 1] = (a.y + b.y + v * c.y) * msk;
    r[j + 2] = (a.z + b.z + v * c.z) * msk;
    r[j + 3] = (a.w + b.w + v * c.w) * msk;
  }
  uint4 o;
  o.x = pack2(r[0], r[1]); o.y = pack2(r[2], r[3]);
  o.z = pack2(r[4], r[5]); o.w = pack2(r[6], r[7]);
  *(uint4*)(Xb + (size_t)gid * 8) = o;
}

// ---------------------------------------------------------------------------
// prep_w: LDS-staged transpose/pack of Ws and W1 (fp32 k-major) into bf16
// MFMA-frag-major. Block tile = 64 K x 128 N. Reads: fully-coalesced float4
// (full 128B lines). Writes: 1KB-contiguous uint4 runs.
// Output chunk c = ((h*128 + NT)*32 + kc2)*64 + lane, elem j:
//   value = W[kc2*32 + (lane>>4)*8 + j][NT*16 + (lane&15)]
// Grid: 4096 W1 blocks (h 16 x kt 16 x nt 16) then 128 Ws blocks (kt 16 x ntw 8).
// ---------------------------------------------------------------------------
__global__ __launch_bounds__(256) void prep_w(
    const float* __restrict__ Ws, const float* __restrict__ W1,
    unsigned short* __restrict__ Wsp, unsigned short* __restrict__ W1p) {
  __shared__ unsigned short T[16384];   // 32 KB: 16 chunk-sets x 64 lanes x 8
  const int tid = threadIdx.x;
  int bid = blockIdx.x;

  const float* src;       // tile origin [k0][n0]
  unsigned short* dstBase;
  size_t chunk0;          // global chunk index of (set 0, lane 0)
  int rowStride;
  if (bid < 4096) {
    int nt = bid & 15, kt = (bid >> 4) & 15, h = bid >> 8;
    src = W1 + ((size_t)h * DD + kt * 64) * FF + nt * 128;
    rowStride = FF;
    chunk0 = (((size_t)h * 128 + nt * 8) * 32 + kt * 2) * 64;
    dstBase = W1p;
  } else {
    int b2i = bid - 4096;
    int ntw = b2i & 7, kt = b2i >> 3;
    src = Ws + (size_t)(kt * 64) * DD + ntw * 128;
    rowStride = DD;
    chunk0 = (((size_t)ntw * 8) * 32 + kt * 2) * 64;
    dstBase = Wsp;
  }

  // Read phase: row r = tid>>2, col group (tid&3)*32, 8 float4 each.
  {
    int r = tid >> 2;
    int cg = (tid & 3) * 32;
    int kc2l = r >> 5, q = (r >> 3) & 3, j = r & 7;
    const float* p = src + (size_t)r * rowStride + cg;
#pragma unroll
    for (int i = 0; i < 8; ++i) {
      float4 v = *(const float4*)(p + i * 4);
      float vv[4] = {v.x, v.y, v.z, v.w};
#pragma unroll
      for (int e = 0; e < 4; ++e) {
        int nl = cg + i * 4 + e;
        int ntl = nl >> 4, cl = nl & 15;
        T[((ntl * 2 + kc2l) * 64 + q * 16 + cl) * 8 + j] = f2bf(vv[e]);
      }
    }
  }
  __syncthreads();

  // Write phase: thread (pp = tid>>6, lane = tid&63) writes sets pp, pp+4, pp+8, pp+12.
  {
    int lane = tid & 63, pp = tid >> 6;
#pragma unroll
    for (int u = 0; u < 4; ++u) {
      int s2 = pp + u * 4;                       // set = ntl*2 + kc2l
      int ntl = s2 >> 1, kc2l = s2 & 1;
      uint4 v = *(const uint4*)&T[(s2 * 64 + lane) * 8];
      size_t cg = chunk0 + ((size_t)ntl * 32 + kc2l) * 64 + lane;
      *(uint4*)(dstBase + cg * 8) = v;
    }
  }
}

// ---------------------------------------------------------------------------
// Stage 1: shared = gelu(X @ Ws + bs). BARRIER-FREE: A-frags loaded directly
// from row-major Xb (16B/lane), B-frags from frag-major Wsp. BK=32, 32 steps
// fully unrolled, depth-1 register prefetch -> compiler emits vmcnt(N>0).
// Block = 4 waves, wave = 64m x 64n. grid (64 m-tiles, 4 n-blocks).
// ---------------------------------------------------------------------------
__global__ __launch_bounds__(256, 2) void gemm1_mfma(
    const unsigned short* __restrict__ Xb, const unsigned short* __restrict__ Wsp,
    const float* __restrict__ bs, unsigned short* __restrict__ shared_bf) {
  const int tid = threadIdx.x;
  const int lane = tid & 63, w = tid >> 6;
  const int m0 = blockIdx.x * 64;
  const int n0 = blockIdx.y * 256 + w * 64;   // wave's n-origin
  const int q = lane >> 4, c = lane & 15;

  // A pointers: row m0 + mt*16 + c, k-offset q*8 (+ s*32 per step)
  const unsigned short* aP[4];
#pragma unroll
  for (int mt = 0; mt < 4; ++mt)
    aP[mt] = Xb + (size_t)(m0 + mt * 16 + c) * DD + q * 8;

  // B pointers: NT = n0/16 + t; chunk (NT*32 + s)*64 + lane
  const unsigned short* bP[4];
#pragma unroll
  for (int t = 0; t < 4; ++t)
    bP[t] = Wsp + (((size_t)(n0 / 16 + t) * 32) * 64 + lane) * 8;

  f32x4 acc[4][4] = {};
  bf16x8 aC[4], bC[4], aN[4], bN[4];

#pragma unroll
  for (int mt = 0; mt < 4; ++mt) aC[mt] = *(const bf16x8*)(aP[mt]);
#pragma unroll
  for (int t = 0; t < 4; ++t) bC[t] = *(const bf16x8*)(bP[t]);

#pragma unroll
  for (int s = 0; s < 32; ++s) {
    if (s < 31) {
#pragma unroll
      for (int mt = 0; mt < 4; ++mt)
        aN[mt] = *(const bf16x8*)(aP[mt] + (s + 1) * 32);
#pragma unroll
      for (int t = 0; t < 4; ++t)
        bN[t] = *(const bf16x8*)(bP[t] + (size_t)(s + 1) * 512);
    }
#pragma unroll
    for (int mt = 0; mt < 4; ++mt)
#pragma unroll
      for (int t = 0; t < 4; ++t)
        acc[mt][t] = __builtin_amdgcn_mfma_f32_16x16x32_bf16(aC[mt], bC[t], acc[mt][t], 0, 0, 0);
#pragma unroll
    for (int mt = 0; mt < 4; ++mt) aC[mt] = aN[mt];
#pragma unroll
    for (int t = 0; t < 4; ++t) bC[t] = bN[t];
  }

  // Epilogue: +bs, gelu, bf16 store. C layout: row = mt*16 + q*4 + r, col = t*16 + c.
  float bsv[4];
#pragma unroll
  for (int t = 0; t < 4; ++t) bsv[t] = bs[n0 + t * 16 + c];
#pragma unroll
  for (int mt = 0; mt < 4; ++mt)
#pragma unroll
    for (int t = 0; t < 4; ++t)
#pragma unroll
      for (int r = 0; r < 4; ++r) {
        int row = m0 + mt * 16 + q * 4 + r;
        int col = n0 + t * 16 + c;
        shared_bf[(size_t)row * DD + col] = f2bf(gelu_f(acc[mt][t][r] + bsv[t]));
      }
}

// ---------------------------------------------------------------------------
// Stage 2: per-head MLP, BARRIER-FREE K-loop. Grid: 1024 blocks, XCD-swizzled
// so all token-tiles of one (h,fc) land on one XCD (same blockIdx mod 8).
// Block = 4 waves, wave = 64 tokens x 64 F. A gathered per-lane directly from
// shared_bf; B from frag-major W1p. Epilogue: gelu(+b1) dot W2, shuffle+LDS
// reduce, atomicAdd into out.
// ---------------------------------------------------------------------------
__global__ __launch_bounds__(256, 2) void gemm2_mfma(
    const unsigned short* __restrict__ shared_bf, const unsigned short* __restrict__ W1p,
    const float* __restrict__ b1, const float* __restrict__ W2,
    const int* __restrict__ counts, const int* __restrict__ lists,
    float* __restrict__ out) {
  // Swizzle decode: bid = ((g>>3)*8 + tile)*8 + (g&7), g = h*8 + fc
  int bid = blockIdx.x;
  int slot = bid & 7;
  int mid  = bid >> 3;
  int tile = mid & 7;
  int g    = (mid >> 3) * 8 + slot;
  int h    = g >> 3;
  int fc   = g & 7;

  const int nt_h = counts[h];
  const int m0 = tile * 64;
  if (m0 >= nt_h) return;

  __shared__ float red[4][68];

  const int tid = threadIdx.x;
  const int lane = tid & 63, w = tid >> 6;
  const int q = lane >> 4, c = lane & 15;
  const int* lp = lists + h * TOK;

  // A pointers: gathered token rows (clamped; dead rows discarded in epilogue)
  const unsigned short* aP[4];
#pragma unroll
  for (int mt = 0; mt < 4; ++mt) {
    int idx = m0 + mt * 16 + c;
    int tok = lp[idx < nt_h ? idx : nt_h - 1];
    aP[mt] = shared_bf + (size_t)tok * DD + q * 8;
  }

  // B pointers: NT = fc*16 + w*4 + t
  const unsigned short* bP[4];
#pragma unroll
  for (int t = 0; t < 4; ++t)
    bP[t] = W1p + (((size_t)(h * 128 + fc * 16 + w * 4 + t) * 32) * 64 + lane) * 8;

  f32x4 acc[4][4] = {};
  bf16x8 aC[4], bC[4], aN[4], bN[4];

#pragma unroll
  for (int mt = 0; mt < 4; ++mt) aC[mt] = *(const bf16x8*)(aP[mt]);
#pragma unroll
  for (int t = 0; t < 4; ++t) bC[t] = *(const bf16x8*)(bP[t]);

#pragma unroll
  for (int s = 0; s < 32; ++s) {
    if (s < 31) {
#pragma unroll
      for (int mt = 0; mt < 4; ++mt)
        aN[mt] = *(const bf16x8*)(aP[mt] + (s + 1) * 32);
#pragma unroll
      for (int t = 0; t < 4; ++t)
        bN[t] = *(const bf16x8*)(bP[t] + (size_t)(s + 1) * 512);
    }
#pragma unroll
    for (int mt = 0; mt < 4; ++mt)
#pragma unroll
      for (int t = 0; t < 4; ++t)
        acc[mt][t] = __builtin_amdgcn_mfma_f32_16x16x32_bf16(aC[mt], bC[t], acc[mt][t], 0, 0, 0);
#pragma unroll
    for (int mt = 0; mt < 4; ++mt) aC[mt] = aN[mt];
#pragma unroll
    for (int t = 0; t < 4; ++t) bC[t] = bN[t];
  }

  // Epilogue: lane cols n = fc*256 + w*64 + t*16 + c
  const float* b1h = b1 + (size_t)h * FF + fc * 256 + w * 64;
  const float* w2h = W2 + (size_t)h * FF + fc * 256 + w * 64;
  float b1v[4], w2v[4];
#pragma unroll
  for (int t = 0; t < 4; ++t) { b1v[t] = b1h[t * 16 + c]; w2v[t] = w2h[t * 16 + c]; }

#pragma unroll
  for (int mt = 0; mt < 4; ++mt)
#pragma unroll
    for (int r = 0; r < 4; ++r) {
      float s = 0.0f;
#pragma unroll
      for (int t = 0; t < 4; ++t)
        s += gelu_f(acc[mt][t][r] + b1v[t]) * w2v[t];
      s += __shfl_xor(s, 1);
      s += __shfl_xor(s, 2);
      s += __shfl_xor(s, 4);
      s += __shfl_xor(s, 8);
      if (c == 0) red[w][mt * 16 + q * 4 + r] = s;
    }
  __syncthreads();

  if (tid < 64) {
    int i = m0 + tid;
    if (i < nt_h) {
      float s = red[0][tid] + red[1][tid] + red[2][tid] + red[3][tid];
      atomicAdd(&out[lp[i]], s);
    }
  }
}

// ---------------------------------------------------------------------------
extern "C" void kernel_launch(void* const* d_in, const int* in_sizes, int n_in,
                              void* d_out, int out_size, void* d_ws, size_t ws_size,
                              hipStream_t stream) {
  const int*   selfies = (const int*)d_in[0];
  const int*   tasks   = (const int*)d_in[1];
  const float* values  = (const float*)d_in[2];
  const int*   pmask   = (const int*)d_in[3];
  const float* emb_s   = (const float*)d_in[4];
  const float* emb_t   = (const float*)d_in[5];
  const float* val_vec = (const float*)d_in[6];
  const float* Ws      = (const float*)d_in[7];
  const float* bs      = (const float*)d_in[8];
  const float* W1      = (const float*)d_in[9];
  const float* b1      = (const float*)d_in[10];
  const float* W2      = (const float*)d_in[11];
  const float* b2      = (const float*)d_in[12];
  float* out = (float*)d_out;

  // Workspace layout (256-B aligned):
  //   Xb        bf16 [4096][1024]   8 MB   @ 0
  //   shared_bf bf16 [4096][1024]   8 MB   @ 8 MB
  //   Wsp       bf16 frag-major     2 MB   @ 16 MB
  //   W1p       bf16 frag-major    64 MB   @ 18 MB
  //   counts    int[16]                    @ 82 MB
  //   lists     int[16*4096]               @ 82 MB + 256
  char* ws = (char*)d_ws;
  unsigned short* Xb        = (unsigned short*)ws;
  unsigned short* shared_bf = (unsigned short*)(ws + (8u << 20));
  unsigned short* Wsp       = (unsigned short*)(ws + (16u << 20));
  unsigned short* W1p       = (unsigned short*)(ws + (18u << 20));
  int* counts = (int*)(ws + (82u << 20));
  int* lists  = (int*)(ws + (82u << 20) + 256);

  hipMemsetAsync(counts, 0, NH * sizeof(int), stream);
  prep_xr<<<TOK * 128 / 256, 256, 0, stream>>>(selfies, tasks, values, pmask,
                                               emb_s, emb_t, val_vec, b2,
                                               Xb, counts, lists, out);
  prep_w<<<4096 + 128, 256, 0, stream>>>(Ws, W1, Wsp, W1p);
  gemm1_mfma<<<dim3(TOK / 64, DD / 256), 256, 0, stream>>>(Xb, Wsp, bs, shared_bf);
  gemm2_mfma<<<1024, 256, 0, stream>>>(shared_bf, W1p, b1, W2, counts, lists, out);
}

// Round 5
// 367.497 us; speedup vs baseline: 1.0567x; 1.0126x over previous
//
#include <hip/hip_runtime.h>
#include <hip/hip_bf16.h>

// B=8, S=512 -> TOK=4096 tokens, D=1024, F=2048, H=16 heads, O=1.
#define TOK 4096
#define DD  1024
#define FF  2048
#define NH  16

typedef short bf16x8 __attribute__((ext_vector_type(8)));
typedef float f32x4  __attribute__((ext_vector_type(4)));

__device__ __forceinline__ float gelu_f(float x) {
  float u = 0.7978845608028654f * (x + 0.044715f * x * x * x);
  float e = __expf(2.0f * u);
  return 0.5f * x * (2.0f - 2.0f / (e + 1.0f));
}

// fp32 -> bf16 round-to-nearest-even
__device__ __forceinline__ unsigned short f2bf(float f) {
  union { float f; unsigned u; } v; v.f = f;
  unsigned r = v.u + 0x7FFF + ((v.u >> 16) & 1);
  return (unsigned short)(r >> 16);
}
__device__ __forceinline__ unsigned pack2(float a, float b) {
  return (unsigned)f2bf(a) | ((unsigned)f2bf(b) << 16);
}

// ---------------------------------------------------------------------------
// prep_fused: blocks [0,4224) transpose/pack W1+Ws into bf16 frag-major
// (LDS-staged, coalesced reads, 1KB-contiguous writes); blocks [4224,6272)
// build Xb (bf16 row-major) + routing lists + out init. One dispatch so the
// gather-latency-bound X build overlaps the BW-bound weight pack.
// Frag-major chunk c = ((h*128 + NT)*32 + kc2)*64 + lane, elem j:
//   value = W[kc2*32 + (lane>>4)*8 + j][NT*16 + (lane&15)]
// ---------------------------------------------------------------------------
__global__ __launch_bounds__(256) void prep_fused(
    const int* __restrict__ selfies, const int* __restrict__ tasks,
    const float* __restrict__ values, const int* __restrict__ pmask,
    const float* __restrict__ emb_s, const float* __restrict__ emb_t,
    const float* __restrict__ val_vec, const float* __restrict__ b2,
    const float* __restrict__ Ws, const float* __restrict__ W1,
    unsigned short* __restrict__ Wsp, unsigned short* __restrict__ W1p,
    unsigned short* __restrict__ Xb, int* __restrict__ counts,
    int* __restrict__ lists, float* __restrict__ out) {
  __shared__ unsigned short T[16384];   // 32 KB: 16 chunk-sets x 64 lanes x 8
  const int tid = threadIdx.x;
  int bid = blockIdx.x;

  if (bid >= 4224) {
    // ---- prep_xr part ----
    int gid = (bid - 4224) * 256 + tid;   // TOK*128 threads
    int kc = (gid & 127) * 8;
    int t  = gid >> 7;
    int sid = selfies[t], tsk = tasks[t];
    if ((gid & 127) == 0) {
      if (tsk > 0) {
        int h = (tsk - 1) & (NH - 1);
        int pos = atomicAdd(&counts[h], 1);
        lists[h * TOK + pos] = t;
        out[t] = b2[h];
      } else {
        out[t] = 0.0f;
      }
    }
    float v = values[t];
    float msk = pmask[t] ? 1.0f : 0.0f;
    const float* ps = emb_s + (size_t)sid * DD + kc;
    const float* pt = emb_t + (size_t)tsk * DD + kc;
    const float* pv = val_vec + kc;
    float r[8];
#pragma unroll
    for (int j = 0; j < 8; j += 4) {
      float4 a = *(const float4*)(ps + j);
      float4 b = *(const float4*)(pt + j);
      float4 c = *(const float4*)(pv + j);
      r[j + 0] = (a.x + b.x + v * c.x) * msk;
      r[j + 1] = (a.y + b.y + v * c.y) * msk;
      r[j + 2] = (a.z + b.z + v * c.z) * msk;
      r[j + 3] = (a.w + b.w + v * c.w) * msk;
    }
    uint4 o;
    o.x = pack2(r[0], r[1]); o.y = pack2(r[2], r[3]);
    o.z = pack2(r[4], r[5]); o.w = pack2(r[6], r[7]);
    *(uint4*)(Xb + (size_t)gid * 8) = o;
    return;
  }

  // ---- prep_w part: tile = 64 K x 128 N ----
  const float* src;
  unsigned short* dstBase;
  size_t chunk0;
  int rowStride;
  if (bid < 4096) {
    int nt = bid & 15, kt = (bid >> 4) & 15, h = bid >> 8;
    src = W1 + ((size_t)h * DD + kt * 64) * FF + nt * 128;
    rowStride = FF;
    chunk0 = (((size_t)h * 128 + nt * 8) * 32 + kt * 2) * 64;
    dstBase = W1p;
  } else {
    int b2i = bid - 4096;
    int ntw = b2i & 7, kt = b2i >> 3;
    src = Ws + (size_t)(kt * 64) * DD + ntw * 128;
    rowStride = DD;
    chunk0 = (((size_t)ntw * 8) * 32 + kt * 2) * 64;
    dstBase = Wsp;
  }

  // Read phase: row r = tid>>2, col group (tid&3)*32, 8 contiguous float4.
  {
    int r = tid >> 2;
    int cg = (tid & 3) * 32;
    int kc2l = r >> 5, q = (r >> 3) & 3, j = r & 7;
    const float* p = src + (size_t)r * rowStride + cg;
#pragma unroll
    for (int i = 0; i < 8; ++i) {
      float4 v = *(const float4*)(p + i * 4);
      float vv[4] = {v.x, v.y, v.z, v.w};
#pragma unroll
      for (int e = 0; e < 4; ++e) {
        int nl = cg + i * 4 + e;
        int ntl = nl >> 4, cl = nl & 15;
        T[((ntl * 2 + kc2l) * 64 + q * 16 + cl) * 8 + j] = f2bf(vv[e]);
      }
    }
  }
  __syncthreads();

  // Write phase: 1KB-contiguous uint4 runs.
  {
    int lane = tid & 63, pp = tid >> 6;
#pragma unroll
    for (int u = 0; u < 4; ++u) {
      int s2 = pp + u * 4;
      int ntl = s2 >> 1, kc2l = s2 & 1;
      uint4 v = *(const uint4*)&T[(s2 * 64 + lane) * 8];
      size_t cg = chunk0 + ((size_t)ntl * 32 + kc2l) * 64 + lane;
      *(uint4*)(dstBase + cg * 8) = v;
    }
  }
}

// ---------------------------------------------------------------------------
// Stage 1: shared = gelu(X @ Ws + bs). Barrier-free, A direct from Xb,
// B from frag-major Wsp, depth-1 register prefetch. Block = 4 waves,
// wave = 64m x 64n. grid (64, 4) = 256 blocks = 1/CU.
// ---------------------------------------------------------------------------
__global__ __launch_bounds__(256, 2) void gemm1_mfma(
    const unsigned short* __restrict__ Xb, const unsigned short* __restrict__ Wsp,
    const float* __restrict__ bs, unsigned short* __restrict__ shared_bf) {
  const int tid = threadIdx.x;
  const int lane = tid & 63, w = tid >> 6;
  const int m0 = blockIdx.x * 64;
  const int n0 = blockIdx.y * 256 + w * 64;
  const int q = lane >> 4, c = lane & 15;

  const unsigned short* aP[4];
#pragma unroll
  for (int mt = 0; mt < 4; ++mt)
    aP[mt] = Xb + (size_t)(m0 + mt * 16 + c) * DD + q * 8;

  const unsigned short* bP[4];
#pragma unroll
  for (int t = 0; t < 4; ++t)
    bP[t] = Wsp + (((size_t)(n0 / 16 + t) * 32) * 64 + lane) * 8;

  f32x4 acc[4][4] = {};
  bf16x8 aC[4], bC[4], aN[4], bN[4];

#pragma unroll
  for (int mt = 0; mt < 4; ++mt) aC[mt] = *(const bf16x8*)(aP[mt]);
#pragma unroll
  for (int t = 0; t < 4; ++t) bC[t] = *(const bf16x8*)(bP[t]);

#pragma unroll
  for (int s = 0; s < 32; ++s) {
    if (s < 31) {
#pragma unroll
      for (int mt = 0; mt < 4; ++mt)
        aN[mt] = *(const bf16x8*)(aP[mt] + (s + 1) * 32);
#pragma unroll
      for (int t = 0; t < 4; ++t)
        bN[t] = *(const bf16x8*)(bP[t] + (size_t)(s + 1) * 512);
    }
#pragma unroll
    for (int mt = 0; mt < 4; ++mt)
#pragma unroll
      for (int t = 0; t < 4; ++t)
        acc[mt][t] = __builtin_amdgcn_mfma_f32_16x16x32_bf16(aC[mt], bC[t], acc[mt][t], 0, 0, 0);
#pragma unroll
    for (int mt = 0; mt < 4; ++mt) aC[mt] = aN[mt];
#pragma unroll
    for (int t = 0; t < 4; ++t) bC[t] = bN[t];
  }

  float bsv[4];
#pragma unroll
  for (int t = 0; t < 4; ++t) bsv[t] = bs[n0 + t * 16 + c];
#pragma unroll
  for (int mt = 0; mt < 4; ++mt)
#pragma unroll
    for (int t = 0; t < 4; ++t)
#pragma unroll
      for (int r = 0; r < 4; ++r) {
        int row = m0 + mt * 16 + q * 4 + r;
        int col = n0 + t * 16 + c;
        shared_bf[(size_t)row * DD + col] = f2bf(gelu_f(acc[mt][t][r] + bsv[t]));
      }
}

// ---------------------------------------------------------------------------
// Stage 2: per-head MLP, barrier-free K-loop, wave = 96 tokens x 64 F
// (24 MFMA per 10 loads). Grid 512, XCD-swizzled: all 4 token-tiles of one
// (h,fc) share blockIdx%8 -> same XCD L2 (B slice fetched once per XCD).
// ---------------------------------------------------------------------------
__global__ __launch_bounds__(256, 2) void gemm2_mfma(
    const unsigned short* __restrict__ shared_bf, const unsigned short* __restrict__ W1p,
    const float* __restrict__ b1, const float* __restrict__ W2,
    const int* __restrict__ counts, const int* __restrict__ lists,
    float* __restrict__ out) {
  // Decode: bid = ((g>>3)*4 + tile)*8 + (g&7), g = h*8 + fc, tile in [0,4)
  int bid = blockIdx.x;
  int slot = bid & 7;
  int mid  = bid >> 3;
  int tile = mid & 3;
  int g    = (mid >> 2) * 8 + slot;
  int h    = g >> 3;
  int fc   = g & 7;

  const int nt_h = counts[h];
  const int m0 = tile * 96;
  if (m0 >= nt_h) return;

  __shared__ float red[4][100];

  const int tid = threadIdx.x;
  const int lane = tid & 63, w = tid >> 6;
  const int q = lane >> 4, c = lane & 15;
  const int* lp = lists + h * TOK;

  // A pointers: gathered token rows (clamped; dead rows discarded in epilogue)
  const unsigned short* aP[6];
#pragma unroll
  for (int mt = 0; mt < 6; ++mt) {
    int idx = m0 + mt * 16 + c;
    int tok = lp[idx < nt_h ? idx : nt_h - 1];
    aP[mt] = shared_bf + (size_t)tok * DD + q * 8;
  }

  // B pointers: NT = fc*16 + w*4 + t
  const unsigned short* bP[4];
#pragma unroll
  for (int t = 0; t < 4; ++t)
    bP[t] = W1p + (((size_t)(h * 128 + fc * 16 + w * 4 + t) * 32) * 64 + lane) * 8;

  f32x4 acc[6][4] = {};
  bf16x8 aC[6], bC[4], aN[6], bN[4];

#pragma unroll
  for (int mt = 0; mt < 6; ++mt) aC[mt] = *(const bf16x8*)(aP[mt]);
#pragma unroll
  for (int t = 0; t < 4; ++t) bC[t] = *(const bf16x8*)(bP[t]);

#pragma unroll
  for (int s = 0; s < 32; ++s) {
    if (s < 31) {
#pragma unroll
      for (int mt = 0; mt < 6; ++mt)
        aN[mt] = *(const bf16x8*)(aP[mt] + (s + 1) * 32);
#pragma unroll
      for (int t = 0; t < 4; ++t)
        bN[t] = *(const bf16x8*)(bP[t] + (size_t)(s + 1) * 512);
    }
#pragma unroll
    for (int mt = 0; mt < 6; ++mt)
#pragma unroll
      for (int t = 0; t < 4; ++t)
        acc[mt][t] = __builtin_amdgcn_mfma_f32_16x16x32_bf16(aC[mt], bC[t], acc[mt][t], 0, 0, 0);
#pragma unroll
    for (int mt = 0; mt < 6; ++mt) aC[mt] = aN[mt];
#pragma unroll
    for (int t = 0; t < 4; ++t) bC[t] = bN[t];
  }

  // Epilogue: lane cols n = fc*256 + w*64 + t*16 + c
  const float* b1h = b1 + (size_t)h * FF + fc * 256 + w * 64;
  const float* w2h = W2 + (size_t)h * FF + fc * 256 + w * 64;
  float b1v[4], w2v[4];
#pragma unroll
  for (int t = 0; t < 4; ++t) { b1v[t] = b1h[t * 16 + c]; w2v[t] = w2h[t * 16 + c]; }

#pragma unroll
  for (int mt = 0; mt < 6; ++mt)
#pragma unroll
    for (int r = 0; r < 4; ++r) {
      float s = 0.0f;
#pragma unroll
      for (int t = 0; t < 4; ++t)
        s += gelu_f(acc[mt][t][r] + b1v[t]) * w2v[t];
      s += __shfl_xor(s, 1);
      s += __shfl_xor(s, 2);
      s += __shfl_xor(s, 4);
      s += __shfl_xor(s, 8);
      if (c == 0) red[w][mt * 16 + q * 4 + r] = s;
    }
  __syncthreads();

  if (tid < 96) {
    int i = m0 + tid;
    if (i < nt_h) {
      float s = red[0][tid] + red[1][tid] + red[2][tid] + red[3][tid];
      atomicAdd(&out[lp[i]], s);
    }
  }
}

// ---------------------------------------------------------------------------
extern "C" void kernel_launch(void* const* d_in, const int* in_sizes, int n_in,
                              void* d_out, int out_size, void* d_ws, size_t ws_size,
                              hipStream_t stream) {
  const int*   selfies = (const int*)d_in[0];
  const int*   tasks   = (const int*)d_in[1];
  const float* values  = (const float*)d_in[2];
  const int*   pmask   = (const int*)d_in[3];
  const float* emb_s   = (const float*)d_in[4];
  const float* emb_t   = (const float*)d_in[5];
  const float* val_vec = (const float*)d_in[6];
  const float* Ws      = (const float*)d_in[7];
  const float* bs      = (const float*)d_in[8];
  const float* W1      = (const float*)d_in[9];
  const float* b1      = (const float*)d_in[10];
  const float* W2      = (const float*)d_in[11];
  const float* b2      = (const float*)d_in[12];
  float* out = (float*)d_out;

  // Workspace layout (256-B aligned):
  //   Xb        bf16 [4096][1024]   8 MB   @ 0
  //   shared_bf bf16 [4096][1024]   8 MB   @ 8 MB
  //   Wsp       bf16 frag-major     2 MB   @ 16 MB
  //   W1p       bf16 frag-major    64 MB   @ 18 MB
  //   counts    int[16]                    @ 82 MB
  //   lists     int[16*4096]               @ 82 MB + 256
  char* ws = (char*)d_ws;
  unsigned short* Xb        = (unsigned short*)ws;
  unsigned short* shared_bf = (unsigned short*)(ws + (8u << 20));
  unsigned short* Wsp       = (unsigned short*)(ws + (16u << 20));
  unsigned short* W1p       = (unsigned short*)(ws + (18u << 20));
  int* counts = (int*)(ws + (82u << 20));
  int* lists  = (int*)(ws + (82u << 20) + 256);

  hipMemsetAsync(counts, 0, NH * sizeof(int), stream);
  prep_fused<<<4224 + 2048, 256, 0, stream>>>(selfies, tasks, values, pmask,
                                              emb_s, emb_t, val_vec, b2,
                                              Ws, W1, Wsp, W1p,
                                              Xb, counts, lists, out);
  gemm1_mfma<<<dim3(TOK / 64, DD / 256), 256, 0, stream>>>(Xb, Wsp, bs, shared_bf);
  gemm2_mfma<<<512, 256, 0, stream>>>(shared_bf, W1p, b1, W2, counts, lists, out);
}